// Round 1
// baseline (96.286 us; speedup 1.0000x reference)
//
#include <hip/hip_runtime.h>
#include <math.h>

// RationalQuadraticSpline: B=65536, V=64, K=30 bins. SINGLE fused kernel.
// R8: (a) LUT entry now u32 {frac16, lo8} -> bucket lookup + boundary probe in
//     ONE ds_read_b32 (was ds_read_u8 + 8-bank-conflicted ds_read_b32).
//     probe = (u + (frac+1)/65536)/128 is EXACT in f32 (23-bit mantissa);
//     knot-quantization window ~1.2e-7, C1 continuity => value error O(eps^2),
//     lad error ~1e-5 (<< current 0.0078 absmax from __logf).
//     DS instr/element: 3 (lut b32, rec b128, deriv read2_b32).
// (b) params fused into the main kernel: every block builds the 64 vars'
//     tables in its own LDS (8 waves x 4 passes, 2 vars/wave in 32-lane
//     halves, ~1.5us redundant VALU) -- kills the params kernel, one launch,
//     and the 37MB global P staging. d_ws unused.
// (c) GRID=512: exactly 4 float4 iters/thread, all blocks co-resident.
//
// LDS layout (dwords):
//   rec: [0, 7936)      stride 124/var: 30 recs x 4 {cumw, 1/w, cumh, h}
//   der: [7936, 10048)  stride 33/var, d[0..30]
//   lut: [10048, 18560) u32, stride 133/var (=5 mod 32: bank spread), 128 bkts
// Total 74240 B -> 2 blocks/CU x 512 thr = 16 waves/CU.

#define NB 65536
#define NV 64
#define NKB 30
#define REC_D 124
#define DER_BASE 7936
#define DER_S 33
#define LUTD_BASE 10048
#define LUT_S 133
#define TOT_D 18560
#define GRID 512
#define BSZ 512

__global__ __launch_bounds__(BSZ, 4) void rqs_fused(const float* __restrict__ x,
                                                    const float* __restrict__ uw,
                                                    const float* __restrict__ uh,
                                                    const float* __restrict__ ud,
                                                    float* __restrict__ out) {
  __shared__ __align__(16) float lds[TOT_D];
  const int tid = threadIdx.x;
  const int wave = tid >> 6;   // 0..7
  const int lane = tid & 63;
  const int half = lane >> 5;  // two vars per wave, one per 32-lane half
  const int hl = lane & 31;
  const float MINB = 1e-3f;
  const float scale = 1.0f - MINB * (float)NKB;

  // ---- params: 4 passes, wave w handles vars 8w..8w+7, 2 at a time ----
  for (int p = 0; p < 4; ++p) {
    const int v = wave * 8 + p * 2 + half;
    // widths: softmax + floor + inclusive scan, all within the 32-lane half
    float u = (hl < NKB) ? uw[v * NKB + hl] : -1e30f;
    float m = u;
#pragma unroll
    for (int s = 16; s >= 1; s >>= 1) m = fmaxf(m, __shfl_xor(m, s));
    float e = (hl < NKB) ? expf(u - m) : 0.0f;
    float t = e;
#pragma unroll
    for (int s = 16; s >= 1; s >>= 1) t += __shfl_xor(t, s);
    float pk = (hl < NKB) ? (MINB + scale * (e / t)) : 0.0f;
    float ci = pk;
#pragma unroll
    for (int s = 1; s < 32; s <<= 1) {
      float z = __shfl_up(ci, s);
      if (hl >= s) ci += z;
    }
    float cw_e = ci - pk;                       // cumw[hl] (exclusive)
    float wnxt = (hl == NKB - 1) ? 1.0f : ci;   // cumw[hl+1], forced hi
    float winv = 1.0f / (wnxt - cw_e);
    // heights
    float uhv = (hl < NKB) ? uh[v * NKB + hl] : -1e30f;
    float mh = uhv;
#pragma unroll
    for (int s = 16; s >= 1; s >>= 1) mh = fmaxf(mh, __shfl_xor(mh, s));
    float eh = (hl < NKB) ? expf(uhv - mh) : 0.0f;
    float th = eh;
#pragma unroll
    for (int s = 16; s >= 1; s >>= 1) th += __shfl_xor(th, s);
    float pkh = (hl < NKB) ? (MINB + scale * (eh / th)) : 0.0f;
    float cih = pkh;
#pragma unroll
    for (int s = 1; s < 32; s <<= 1) {
      float z = __shfl_up(cih, s);
      if (hl >= s) cih += z;
    }
    float ch_e = cih - pkh;
    float hnxt = (hl == NKB - 1) ? 1.0f : cih;
    float hh = hnxt - ch_e;
    if (hl < NKB) {
      float4 r = {cw_e, winv, ch_e, hh};
      *(float4*)(lds + v * REC_D + 4 * hl) = r;
    }
    // derivatives: pad with CONST so softplus(CONST)+MIN_D == 1
    {
      const float CST = (float)log(exp(1.0 - 1e-3) - 1.0);
      if (hl <= NKB) {
        float xd = (hl == 0 || hl == NKB) ? CST : ud[v * (NKB - 1) + hl - 1];
        float sp = (xd > 0.f) ? (xd + log1pf(expf(-xd))) : log1pf(expf(xd));
        lds[DER_BASE + v * DER_S + hl] = 1e-3f + sp;
      }
    }
    // fused LUT: per bucket u, entry = {frac:16, lo:8}
    //   lo   = #{k in [1..29]: cumw[k] <= u/128}   (cumw[30]=1 > u/128 always)
    //   frac = knot-in-bucket ? floor((cumw[lo+1]*128 - u)*65536) : 0xFFFF
    // main decodes probe = (u + (frac+1)/65536)/128 -- exact f32 arithmetic.
    {
      float tb[4];
      int lo[4];
#pragma unroll
      for (int q = 0; q < 4; ++q) {
        tb[q] = (float)(hl + 32 * q) * (1.0f / 128.0f);
        lo[q] = 0;
      }
      for (int kk = 0; kk < NKB - 1; ++kk) {
        float c = __shfl(wnxt, (half << 5) + kk);  // cumw[kk+1]
#pragma unroll
        for (int q = 0; q < 4; ++q) lo[q] += (c <= tb[q]) ? 1 : 0;
      }
#pragma unroll
      for (int q = 0; q < 4; ++q) {
        int ub = hl + 32 * q;
        float knot = __shfl(wnxt, (half << 5) + lo[q]);  // cumw[lo+1], lo<=29
        float top = (float)(ub + 1) * (1.0f / 128.0f);
        int frac;
        if (knot < top) {
          frac = (int)((knot * 128.0f - (float)ub) * 65536.0f);
          frac = frac > 65535 ? 65535 : frac;
        } else {
          frac = 65535;  // no knot in bucket: probe = bucket top, never bumps
        }
        ((unsigned int*)lds)[LUTD_BASE + v * LUT_S + ub] =
            ((unsigned int)frac << 16) | (unsigned int)lo[q];
      }
    }
  }
  __syncthreads();

  // ---- main loop: 3 DS ops/element ----
  const int N = NB * NV;
  const int n4 = N / 4;
  const int gid0 = blockIdx.x * BSZ + tid;
  const int v0 = (gid0 & 15) * 4;  // constant per thread (stride % 16 == 0)
  int baseR[4], baseD[4], baseL[4];
#pragma unroll
  for (int j = 0; j < 4; ++j) {
    const int vj = v0 + j;
    baseR[j] = vj * REC_D;
    baseD[j] = DER_BASE + vj * DER_S;
    baseL[j] = LUTD_BASE + vj * LUT_S;
  }
  const unsigned int* lutu = (const unsigned int*)lds;

  for (int gid = gid0; gid < n4; gid += GRID * BSZ) {  // exactly 4 iters
    float4 xv = ((const float4*)x)[gid];
    float xs[4] = {xv.x, xv.y, xv.z, xv.w};
    float o[4], l[4];
#pragma unroll
    for (int j = 0; j < 4; ++j) {
      float xx = xs[j];
      int ui = (int)(xx * 128.0f);  // exact: x * 2^7
      ui = ui < 0 ? 0 : (ui > 127 ? 127 : ui);
      unsigned int en = lutu[baseL[j] + ui];             // ds_read_b32
      int lo = (int)(en & 0xFFu);
      float probe = ((float)ui + (float)((en >> 16) + 1u) * (1.0f / 65536.0f)) *
                    (1.0f / 128.0f);
      int b = lo + ((xx >= probe) ? 1 : 0);
      b = b > 29 ? 29 : b;
      float4 r4 = *(const float4*)&lds[baseR[j] + 4 * b];  // ds_read_b128
      float d0 = lds[baseD[j] + b];                        // ds_read2_b32
      float d1 = lds[baseD[j] + b + 1];
      float icw = r4.x, winv = r4.y, ich = r4.z, ih = r4.w;
      float idl  = ih * winv;  // delta = h/w
      float thx  = (xx - icw) * winv;
      float omt  = 1.0f - thx;
      float t1mt = thx * omt;
      float th2  = thx * thx;
      float num  = ih * (idl * th2 + d0 * t1mt);
      float den  = idl + (d0 + d1 - 2.0f * idl) * t1mt;
      float rden = __builtin_amdgcn_rcpf(den);  // v_rcp_f32
      float so   = ich + num * rden;
      float dn   = idl * idl * (d1 * th2 + 2.0f * idl * t1mt + d0 * omt * omt);
      float sl   = __logf(dn * rden * rden);    // log(dn) - 2*log(den)
      bool inside = !(xx < 0.0f) && !(xx > 1.0f);
      o[j] = inside ? so : xx;   // DERIV_OUT = 1 -> identity outside
      l[j] = inside ? sl : 0.0f;
    }
    float4 ov = {o[0], o[1], o[2], o[3]};
    float4 lv = {l[0], l[1], l[2], l[3]};
    ((float4*)out)[gid] = ov;
    ((float4*)(out + N))[gid] = lv;
  }
}

extern "C" void kernel_launch(void* const* d_in, const int* in_sizes, int n_in,
                              void* d_out, int out_size, void* d_ws, size_t ws_size,
                              hipStream_t stream) {
  const float* x  = (const float*)d_in[0];
  const float* uw = (const float*)d_in[1];
  const float* uh = (const float*)d_in[2];
  const float* ud = (const float*)d_in[3];
  float* out = (float*)d_out;
  (void)d_ws; (void)ws_size;

  rqs_fused<<<GRID, BSZ, 0, stream>>>(x, uw, uh, ud, out);
}

// Round 2
// 87.628 us; speedup vs baseline: 1.0988x; 1.0988x over previous
//
#include <hip/hip_runtime.h>
#include <math.h>

// RationalQuadraticSpline: B=65536, V=64, K=30 bins. TWO kernels (R8 fusion
// regressed +11us: redundant per-block param prologue put ~150 shfl/thread on
// the DS pipe at reduced occupancy -- reverted).
// R9 keeps R8's LUT fusion only: LUT entry u32 {frac:16, lo:8} -> bucket
// lookup + boundary probe in ONE ds_read_b32 (was ds_read_u8 + 8-bank-aliased
// probe ds_read_b32). probe = (u + (frac+1)/65536)/128 is EXACT in f32
// (7+16 <= 23 mantissa bits); misclassification window per knot ~1.2e-7, and
// the spline is C1 at knots => value/lad error << current 0.0078 absmax.
// Main loop DS ops/element: 3 (lut b32, rec b128, deriv read2_b32).
//
// LDS/P layout (dwords):
//   rec: [0, 7936)      stride 124/var (=28 mod 32: v-groups spread banks),
//                       30 recs x4 {cumw, 1/w, cumh, h}; slot 30 unused
//   der: [7936, 9920)   stride 31/var (= -1 mod 32: spread), d[0..30]
//   lut: [9920, 18432)  u32, stride 133/var (=5 mod 32), 128 buckets
// Total 73728 B -> 2 blocks/CU x 512 thr = 16 waves/CU. GRID=512: all blocks
// co-resident, exactly 4 float4 iters/thread.
// LUT exactness precondition: logits in [0,1) => min bin width >= 0.01316 >
// 1/128, so any bucket holds <= 1 knot => bin = lo + one compare.

#define NB 65536
#define NV 64
#define NKB 30
#define REC_D 124
#define DER_BASE 7936
#define DER_S 31
#define LUTD_BASE 9920
#define LUT_S 133
#define TOT_D 18432
#define GRID 512
#define BSZ 512

__global__ __launch_bounds__(64) void rqs_params(const float* __restrict__ uw,
                                                 const float* __restrict__ uh,
                                                 const float* __restrict__ ud,
                                                 float* __restrict__ P) {
  const int v = blockIdx.x;
  const int lane = threadIdx.x;
  const float MINB = 1e-3f;
  const float scale = 1.0f - MINB * (float)NKB;

  // ---- widths: softmax + floor + scan (all shuffles full-wave) ----
  float cw_e, winv, wnxt;
  {
    float u = (lane < NKB) ? uw[v * NKB + lane] : -1e30f;
    float m = u;
#pragma unroll
    for (int s = 32; s >= 1; s >>= 1) m = fmaxf(m, __shfl_xor(m, s));
    float e = (lane < NKB) ? expf(u - m) : 0.0f;
    float t = e;
#pragma unroll
    for (int s = 32; s >= 1; s >>= 1) t += __shfl_xor(t, s);
    float pk = (lane < NKB) ? (MINB + scale * (e / t)) : 0.0f;
    float ci = pk;
#pragma unroll
    for (int s = 1; s < 64; s <<= 1) {
      float z = __shfl_up(ci, s);
      if (lane >= s) ci += z;
    }
    cw_e = ci - pk;                            // cumw[lane] (exclusive)
    wnxt = (lane == NKB - 1) ? 1.0f : ci;      // cumw[lane+1], forced hi
    winv = 1.0f / (wnxt - cw_e);
  }
  // ---- heights ----
  float ch_e, hh;
  {
    float u = (lane < NKB) ? uh[v * NKB + lane] : -1e30f;
    float m = u;
#pragma unroll
    for (int s = 32; s >= 1; s >>= 1) m = fmaxf(m, __shfl_xor(m, s));
    float e = (lane < NKB) ? expf(u - m) : 0.0f;
    float t = e;
#pragma unroll
    for (int s = 32; s >= 1; s >>= 1) t += __shfl_xor(t, s);
    float pk = (lane < NKB) ? (MINB + scale * (e / t)) : 0.0f;
    float ci = pk;
#pragma unroll
    for (int s = 1; s < 64; s <<= 1) {
      float z = __shfl_up(ci, s);
      if (lane >= s) ci += z;
    }
    ch_e = ci - pk;
    float hnxt = (lane == NKB - 1) ? 1.0f : ci;
    hh = hnxt - ch_e;
  }
  // ---- packed records ----
  if (lane < NKB) {
    float4 r = {cw_e, winv, ch_e, hh};
    *(float4*)(P + v * REC_D + 4 * lane) = r;
  }
  // ---- derivatives: pad with CONST so softplus(CONST)+MIN_D == 1 ----
  {
    const float CST = (float)log(exp(1.0 - 1e-3) - 1.0);
    if (lane <= NKB) {
      float x = (lane == 0 || lane == NKB) ? CST : ud[v * (NKB - 1) + lane - 1];
      float sp = (x > 0.f) ? (x + log1pf(expf(-x))) : log1pf(expf(x));
      P[DER_BASE + v * DER_S + lane] = 1e-3f + sp;
    }
  }
  // ---- fused LUT: bucket ub -> {frac:16, lo:8} ----
  //   lo   = #{k in [1..29]: cumw[k] <= ub/128}
  //   knot = cumw[lo+1];  frac encodes the knot position inside the bucket:
  //   main decodes probe = (ub + (frac+1)/65536)/128  (exact f32), with
  //   knot < probe <= knot + 1.2e-7, so "x >= probe" == "x > knot" outside
  //   a 1.2e-7 window where C1 continuity makes the error negligible.
  {
    float t0 = (float)lane * (1.0f / 128.0f);
    float t1 = (float)(lane + 64) * (1.0f / 128.0f);
    int lo0 = 0, lo1 = 0;
#pragma unroll
    for (int kk = 0; kk < NKB - 1; ++kk) {     // k = 1..29 (cumw[30]=1 > t)
      float c = __shfl(wnxt, kk);              // cumw[kk+1]; full-wave shuffle
      lo0 += (c <= t0) ? 1 : 0;
      lo1 += (c <= t1) ? 1 : 0;
    }
    float k0 = __shfl(wnxt, lo0);              // cumw[lo0+1], lo0 <= 29
    float k1 = __shfl(wnxt, lo1);
    unsigned int* Pu = (unsigned int*)P;
    {
      float top = (float)(lane + 1) * (1.0f / 128.0f);
      int frac = 65535;
      if (k0 < top) {
        frac = (int)((k0 * 128.0f - (float)lane) * 65536.0f);
        frac = frac > 65535 ? 65535 : frac;
      }
      Pu[LUTD_BASE + v * LUT_S + lane] =
          ((unsigned int)frac << 16) | (unsigned int)lo0;
    }
    {
      float top = (float)(lane + 65) * (1.0f / 128.0f);
      int frac = 65535;
      if (k1 < top) {
        frac = (int)((k1 * 128.0f - (float)(lane + 64)) * 65536.0f);
        frac = frac > 65535 ? 65535 : frac;
      }
      Pu[LUTD_BASE + v * LUT_S + lane + 64] =
          ((unsigned int)frac << 16) | (unsigned int)lo1;
    }
  }
}

__global__ __launch_bounds__(BSZ, 4) void rqs_main(const float* __restrict__ x,
                                                   const float* __restrict__ P,
                                                   float* __restrict__ out) {
  __shared__ __align__(16) float lds[TOT_D];  // 73728 B -> 2 blocks/CU
  for (int i = threadIdx.x; i < TOT_D / 4; i += BSZ)  // 9 exact iters
    ((float4*)lds)[i] = ((const float4*)P)[i];
  __syncthreads();
  const unsigned int* lutu = (const unsigned int*)lds;

  const int N = NB * NV;
  const int n4 = N / 4;  // 1048576 float4 groups
  const int gid0 = blockIdx.x * BSZ + threadIdx.x;
  const int v0 = (gid0 & 15) * 4;  // constant per thread (stride % 16 == 0)
  int baseR[4], baseD[4], baseL[4];
#pragma unroll
  for (int j = 0; j < 4; ++j) {
    const int vj = v0 + j;
    baseR[j] = vj * REC_D;
    baseD[j] = DER_BASE + vj * DER_S;
    baseL[j] = LUTD_BASE + vj * LUT_S;
  }

  for (int gid = gid0; gid < n4; gid += GRID * BSZ) {  // exactly 4 iters
    float4 xv = ((const float4*)x)[gid];
    float xs[4] = {xv.x, xv.y, xv.z, xv.w};
    float o[4], l[4];
#pragma unroll
    for (int j = 0; j < 4; ++j) {
      float xx = xs[j];
      int ui = (int)(xx * 128.0f);  // exact: x * 2^7
      ui = ui < 0 ? 0 : (ui > 127 ? 127 : ui);
      unsigned int en = lutu[baseL[j] + ui];               // ds_read_b32
      int lo = (int)(en & 0xFFu);
      float probe = ((float)ui + (float)((en >> 16) + 1u) * (1.0f / 65536.0f)) *
                    (1.0f / 128.0f);
      int b = lo + ((xx >= probe) ? 1 : 0);
      b = b > 29 ? 29 : b;
      float4 r4 = *(const float4*)&lds[baseR[j] + 4 * b];  // ds_read_b128
      float d0 = lds[baseD[j] + b];                        // ds_read2_b32
      float d1 = lds[baseD[j] + b + 1];
      float icw = r4.x, winv = r4.y, ich = r4.z, ih = r4.w;
      float idl  = ih * winv;  // delta = h/w
      float thx  = (xx - icw) * winv;
      float omt  = 1.0f - thx;
      float t1mt = thx * omt;
      float th2  = thx * thx;
      float num  = ih * (idl * th2 + d0 * t1mt);
      float den  = idl + (d0 + d1 - 2.0f * idl) * t1mt;
      float rden = __builtin_amdgcn_rcpf(den);  // v_rcp_f32
      float so   = ich + num * rden;
      float dn   = idl * idl * (d1 * th2 + 2.0f * idl * t1mt + d0 * omt * omt);
      float sl   = __logf(dn * rden * rden);    // log(dn) - 2*log(den)
      bool inside = !(xx < 0.0f) && !(xx > 1.0f);
      o[j] = inside ? so : xx;   // DERIV_OUT = 1 -> identity outside
      l[j] = inside ? sl : 0.0f;
    }
    float4 ov = {o[0], o[1], o[2], o[3]};
    float4 lv = {l[0], l[1], l[2], l[3]};
    ((float4*)out)[gid] = ov;
    ((float4*)(out + N))[gid] = lv;
  }
}

extern "C" void kernel_launch(void* const* d_in, const int* in_sizes, int n_in,
                              void* d_out, int out_size, void* d_ws, size_t ws_size,
                              hipStream_t stream) {
  const float* x  = (const float*)d_in[0];
  const float* uw = (const float*)d_in[1];
  const float* uh = (const float*)d_in[2];
  const float* ud = (const float*)d_in[3];
  float* out = (float*)d_out;
  float* P   = (float*)d_ws;  // 73728 B used

  rqs_params<<<NV, 64, 0, stream>>>(uw, uh, ud, P);
  rqs_main<<<GRID, BSZ, 0, stream>>>(x, P, out);
}

// Round 3
// 85.346 us; speedup vs baseline: 1.1282x; 1.0267x over previous
//
#include <hip/hip_runtime.h>
#include <math.h>

// RationalQuadraticSpline: B=65536, V=64, K=30 bins. TWO kernels.
// History: R8 fusion +11us (prologue on DS pipe, 16 waves). R9 (LUT-fused
// u32 probe, 3 DS ops/elem, 16 waves/CU) = 87.6 vs baseline 85.4 despite
// -1 DS op => main loop is LATENCY-bound (chain: lut b32 -> cmp -> b128 +
// read2 -> ~30 VALU -> log; ~2 serial LDS latencies/elem), not DS-issue
// bound (issue model ~2.5us/CU << observed ~27us).
// R10: same tables/DS structure as R9, occupancy 16 -> 32 waves/CU (HW max):
//   BSZ 1024, GRID 512 -> 2 blocks/CU x 16 waves, exactly 2 iters/thread.
//   __launch_bounds__(1024, 8) caps VGPR at 64; per-table base registers
//   collapsed 12 -> 3 (j*stride folds into the DS imm offset) to fit.
//
// LDS/P layout (dwords):
//   rec: [0, 7936)      stride 124/var, 30 recs x4 {cumw, 1/w, cumh, h}
//   der: [7936, 9920)   stride 31/var, d[0..30]
//   lut: [9920, 18432)  u32 {frac:16, lo:8}, stride 133/var, 128 buckets
// Total 73728 B -> 2 blocks/CU.
// LUT exactness: min bin width >= 0.01316 > 1/128 -> <=1 knot per bucket;
// probe = (u + (frac+1)/65536)/128 exact in f32 (7+16 <= 23 mantissa bits).

#define NB 65536
#define NV 64
#define NKB 30
#define REC_D 124
#define DER_BASE 7936
#define DER_S 31
#define LUTD_BASE 9920
#define LUT_S 133
#define TOT_D 18432
#define GRID 512
#define BSZ 1024

__global__ __launch_bounds__(64) void rqs_params(const float* __restrict__ uw,
                                                 const float* __restrict__ uh,
                                                 const float* __restrict__ ud,
                                                 float* __restrict__ P) {
  const int v = blockIdx.x;
  const int lane = threadIdx.x;
  const float MINB = 1e-3f;
  const float scale = 1.0f - MINB * (float)NKB;

  // ---- widths: softmax + floor + scan (all shuffles full-wave) ----
  float cw_e, winv, wnxt;
  {
    float u = (lane < NKB) ? uw[v * NKB + lane] : -1e30f;
    float m = u;
#pragma unroll
    for (int s = 32; s >= 1; s >>= 1) m = fmaxf(m, __shfl_xor(m, s));
    float e = (lane < NKB) ? expf(u - m) : 0.0f;
    float t = e;
#pragma unroll
    for (int s = 32; s >= 1; s >>= 1) t += __shfl_xor(t, s);
    float pk = (lane < NKB) ? (MINB + scale * (e / t)) : 0.0f;
    float ci = pk;
#pragma unroll
    for (int s = 1; s < 64; s <<= 1) {
      float z = __shfl_up(ci, s);
      if (lane >= s) ci += z;
    }
    cw_e = ci - pk;                            // cumw[lane] (exclusive)
    wnxt = (lane == NKB - 1) ? 1.0f : ci;      // cumw[lane+1], forced hi
    winv = 1.0f / (wnxt - cw_e);
  }
  // ---- heights ----
  float ch_e, hh;
  {
    float u = (lane < NKB) ? uh[v * NKB + lane] : -1e30f;
    float m = u;
#pragma unroll
    for (int s = 32; s >= 1; s >>= 1) m = fmaxf(m, __shfl_xor(m, s));
    float e = (lane < NKB) ? expf(u - m) : 0.0f;
    float t = e;
#pragma unroll
    for (int s = 32; s >= 1; s >>= 1) t += __shfl_xor(t, s);
    float pk = (lane < NKB) ? (MINB + scale * (e / t)) : 0.0f;
    float ci = pk;
#pragma unroll
    for (int s = 1; s < 64; s <<= 1) {
      float z = __shfl_up(ci, s);
      if (lane >= s) ci += z;
    }
    ch_e = ci - pk;
    float hnxt = (lane == NKB - 1) ? 1.0f : ci;
    hh = hnxt - ch_e;
  }
  // ---- packed records ----
  if (lane < NKB) {
    float4 r = {cw_e, winv, ch_e, hh};
    *(float4*)(P + v * REC_D + 4 * lane) = r;
  }
  // ---- derivatives: pad with CONST so softplus(CONST)+MIN_D == 1 ----
  {
    const float CST = (float)log(exp(1.0 - 1e-3) - 1.0);
    if (lane <= NKB) {
      float x = (lane == 0 || lane == NKB) ? CST : ud[v * (NKB - 1) + lane - 1];
      float sp = (x > 0.f) ? (x + log1pf(expf(-x))) : log1pf(expf(x));
      P[DER_BASE + v * DER_S + lane] = 1e-3f + sp;
    }
  }
  // ---- fused LUT: bucket ub -> {frac:16, lo:8} ----
  //   lo   = #{k in [1..29]: cumw[k] <= ub/128}
  //   main decodes probe = (ub + (frac+1)/65536)/128 (exact f32), with
  //   knot < probe <= knot + 1.2e-7; C1 continuity makes the window harmless.
  {
    float t0 = (float)lane * (1.0f / 128.0f);
    float t1 = (float)(lane + 64) * (1.0f / 128.0f);
    int lo0 = 0, lo1 = 0;
#pragma unroll
    for (int kk = 0; kk < NKB - 1; ++kk) {     // k = 1..29 (cumw[30]=1 > t)
      float c = __shfl(wnxt, kk);              // cumw[kk+1]; full-wave shuffle
      lo0 += (c <= t0) ? 1 : 0;
      lo1 += (c <= t1) ? 1 : 0;
    }
    float k0 = __shfl(wnxt, lo0);              // cumw[lo0+1], lo0 <= 29
    float k1 = __shfl(wnxt, lo1);
    unsigned int* Pu = (unsigned int*)P;
    {
      float top = (float)(lane + 1) * (1.0f / 128.0f);
      int frac = 65535;
      if (k0 < top) {
        frac = (int)((k0 * 128.0f - (float)lane) * 65536.0f);
        frac = frac > 65535 ? 65535 : frac;
      }
      Pu[LUTD_BASE + v * LUT_S + lane] =
          ((unsigned int)frac << 16) | (unsigned int)lo0;
    }
    {
      float top = (float)(lane + 65) * (1.0f / 128.0f);
      int frac = 65535;
      if (k1 < top) {
        frac = (int)((k1 * 128.0f - (float)(lane + 64)) * 65536.0f);
        frac = frac > 65535 ? 65535 : frac;
      }
      Pu[LUTD_BASE + v * LUT_S + lane + 64] =
          ((unsigned int)frac << 16) | (unsigned int)lo1;
    }
  }
}

__global__ __launch_bounds__(BSZ, 8) void rqs_main(const float* __restrict__ x,
                                                   const float* __restrict__ P,
                                                   float* __restrict__ out) {
  __shared__ __align__(16) float lds[TOT_D];  // 73728 B -> 2 blocks/CU
  for (int i = threadIdx.x; i < TOT_D / 4; i += BSZ)
    ((float4*)lds)[i] = ((const float4*)P)[i];
  __syncthreads();
  const unsigned int* lutu = (const unsigned int*)lds;

  const int N = NB * NV;
  const int n4 = N / 4;  // 1048576 float4 groups
  const int gid0 = blockIdx.x * BSZ + threadIdx.x;
  const int v0 = (gid0 & 15) * 4;  // constant per thread (stride % 16 == 0)
  // single base per table; j*stride folds into the DS immediate offset
  const int bR = v0 * REC_D;
  const int bD = DER_BASE + v0 * DER_S;
  const int bL = LUTD_BASE + v0 * LUT_S;

  for (int gid = gid0; gid < n4; gid += GRID * BSZ) {  // exactly 2 iters
    float4 xv = ((const float4*)x)[gid];
    float xs[4] = {xv.x, xv.y, xv.z, xv.w};
    float o[4], l[4];
#pragma unroll
    for (int j = 0; j < 4; ++j) {
      float xx = xs[j];
      int ui = (int)(xx * 128.0f);  // exact: x * 2^7
      ui = ui < 0 ? 0 : (ui > 127 ? 127 : ui);
      unsigned int en = lutu[bL + j * LUT_S + ui];         // ds_read_b32
      int lo = (int)(en & 0xFFu);
      float probe = ((float)ui + (float)((en >> 16) + 1u) * (1.0f / 65536.0f)) *
                    (1.0f / 128.0f);
      int b = lo + ((xx >= probe) ? 1 : 0);
      b = b > 29 ? 29 : b;
      float4 r4 = *(const float4*)&lds[bR + j * REC_D + 4 * b];  // ds_read_b128
      float d0 = lds[bD + j * DER_S + b];                  // ds_read2_b32
      float d1 = lds[bD + j * DER_S + b + 1];
      float icw = r4.x, winv = r4.y, ich = r4.z, ih = r4.w;
      float idl  = ih * winv;  // delta = h/w
      float thx  = (xx - icw) * winv;
      float omt  = 1.0f - thx;
      float t1mt = thx * omt;
      float th2  = thx * thx;
      float num  = ih * (idl * th2 + d0 * t1mt);
      float den  = idl + (d0 + d1 - 2.0f * idl) * t1mt;
      float rden = __builtin_amdgcn_rcpf(den);  // v_rcp_f32
      float so   = ich + num * rden;
      float dn   = idl * idl * (d1 * th2 + 2.0f * idl * t1mt + d0 * omt * omt);
      float sl   = __logf(dn * rden * rden);    // log(dn) - 2*log(den)
      bool inside = !(xx < 0.0f) && !(xx > 1.0f);
      o[j] = inside ? so : xx;   // DERIV_OUT = 1 -> identity outside
      l[j] = inside ? sl : 0.0f;
    }
    float4 ov = {o[0], o[1], o[2], o[3]};
    float4 lv = {l[0], l[1], l[2], l[3]};
    ((float4*)out)[gid] = ov;
    ((float4*)(out + N))[gid] = lv;
  }
}

extern "C" void kernel_launch(void* const* d_in, const int* in_sizes, int n_in,
                              void* d_out, int out_size, void* d_ws, size_t ws_size,
                              hipStream_t stream) {
  const float* x  = (const float*)d_in[0];
  const float* uw = (const float*)d_in[1];
  const float* uh = (const float*)d_in[2];
  const float* ud = (const float*)d_in[3];
  float* out = (float*)d_out;
  float* P   = (float*)d_ws;  // 73728 B used

  rqs_params<<<NV, 64, 0, stream>>>(uw, uh, ud, P);
  rqs_main<<<GRID, BSZ, 0, stream>>>(x, P, out);
}